// Round 3
// baseline (1276.518 us; speedup 1.0000x reference)
//
#include <hip/hip_runtime.h>
#include <hip/hip_bf16.h>

// Problem constants (from setup_inputs)
#define TT 4
#define WAYN 5
#define SHOTN 5
#define WQN 75          // way*query = 5*15
#define CC 640
#define HWN 100
#define YN 500          // shot*hw
#define YPADN 512
#define XPADN 112       // 100 padded to 7*16
#define KT 64           // K chunk

typedef __attribute__((ext_vector_type(8))) short bf16x8;
typedef __attribute__((ext_vector_type(4))) float f32x4;

__device__ __forceinline__ unsigned short f2bf(float f) {
  unsigned int u = __float_as_uint(f);
  u += 0x7fffu + ((u >> 16) & 1u);   // RNE
  return (unsigned short)(u >> 16);
}

// branchless insert of v into sorted triple t1>=t2>=t3
__device__ __forceinline__ void ins3(float v, float& t1, float& t2, float& t3) {
  float a1 = fmaxf(t1, v), d1 = fminf(t1, v);
  float a2 = fmaxf(t2, d1), d2 = fminf(t2, d1);
  float a3 = fmaxf(t3, d2);
  t1 = a1; t2 = a2; t3 = a3;
}

// qinv[t,wq,c] = 1/max(||q[t,wq,c,:]||,eps)  — one wave per (t,wq,c) row of 100
__global__ void dn4_qinv(const float* __restrict__ q, float* __restrict__ qinv) {
  int row = blockIdx.x * 4 + (threadIdx.x >> 6);
  int lane = threadIdx.x & 63;
  const float* p = q + (size_t)row * HWN;
  float ss = 0.f;
  if (lane < 50) { float2 v = ((const float2*)p)[lane]; ss = v.x * v.x + v.y * v.y; }
  #pragma unroll
  for (int off = 32; off; off >>= 1) ss += __shfl_down(ss, off);
  if (lane == 0) qinv[row] = 1.f / fmaxf(sqrtf(ss), 1e-12f);
}

// sinv[t,way,y] = 1/max(||s[t,way,:,y]||,eps) — block per (t,sidx), 4 c-chunks x 128 pos
__global__ void dn4_sinv(const float* __restrict__ s, float* __restrict__ sinv) {
  __shared__ float ps[4][128];
  int b = blockIdx.x;                       // t*25 + sidx
  int cg = threadIdx.x >> 7, pos = threadIdx.x & 127;
  float ss = 0.f;
  if (pos < HWN) {
    const float* p = s + ((size_t)b * CC + cg * 160) * HWN + pos;
    #pragma unroll 8
    for (int c = 0; c < 160; ++c) { float v = p[c * HWN]; ss += v * v; }
  }
  ps[cg][pos] = ss;
  __syncthreads();
  if (cg == 0 && pos < HWN) {
    float tot = ps[0][pos] + ps[1][pos] + ps[2][pos] + ps[3][pos];
    int t = b / 25, sidx = b % 25, way = sidx / 5, shot = sidx % 5;
    sinv[(t * WAYN + way) * YN + shot * HWN + pos] = 1.f / fmaxf(sqrtf(tot), 1e-12f);
  }
}

// Main fused kernel: block = (t, way, wq). Computes full 112x512 relation in
// registers (MFMA, K-outer), then fused top-3-per-row + sum.
__global__ __launch_bounds__(512, 2)
void dn4_main(const float* __restrict__ q, const float* __restrict__ s,
              const float* __restrict__ qinv, const float* __restrict__ sinv,
              float* __restrict__ out) {
  // swizzled bf16 operand tiles: [row][64 k], col ^= (row&7)*8 (16B-slot XOR swizzle)
  __shared__ __align__(16) unsigned short aT[XPADN * 64];
  __shared__ __align__(16) unsigned short bT[YPADN * 64];
  __shared__ float part3[8][XPADN][3];
  __shared__ float rowsum[XPADN];

  int bid = blockIdx.x;
  int wq = bid % WQN;
  int tw = bid / WQN;          // t*WAYN + way  (B-locality-major ordering)
  int way = tw % WAYN;
  int t = tw / WAYN;

  int tid = threadIdx.x;
  int lane = tid & 63;
  int wv = tid >> 6;           // wave 0..7, owns y-slice [64*wv, 64*wv+64)
  int m = lane & 15, g = lane >> 4;

  const float* qb = q + ((size_t)(t * WQN + wq) * CC) * HWN;        // [c][x]
  const float* sb = s + ((size_t)(t * 25 + way * SHOTN) * CC) * HWN; // [shot][c][pos]
  const float* qinvb = qinv + (t * WQN + wq) * CC;
  const float* sinvb = sinv + (t * WAYN + way) * YN;

  f32x4 acc[7][4];
  #pragma unroll
  for (int i = 0; i < 7; ++i) {
    #pragma unroll
    for (int j = 0; j < 4; ++j) acc[i][j] = (f32x4){0.f, 0.f, 0.f, 0.f};
  }

  for (int kc = 0; kc < CC; kc += KT) {
    __syncthreads();
    // stage A: element (x, kk) <- q[kc+kk][x] * qinv[kc+kk], transposed, bf16
    #pragma unroll
    for (int it = 0; it < 16; ++it) {
      int e = tid + it * 512;
      int kk = e >> 7, xx = e & 127;
      if (xx < XPADN) {
        float v = 0.f;
        if (xx < HWN) v = qb[(kc + kk) * HWN + xx] * qinvb[kc + kk];
        aT[xx * 64 + (kk ^ ((xx & 7) * 8))] = f2bf(v);
      }
    }
    // stage B: element (y, kk) <- s[shot][kc+kk][pos], transposed, bf16 (pad y -> 0)
    #pragma unroll
    for (int it = 0; it < 16; ++it) {
      int e = tid + it * 512;
      int kk = e >> 7, yg = e & 127;
      int y0 = yg * 4;
      float4 v = make_float4(0.f, 0.f, 0.f, 0.f);
      if (y0 < YN) {
        int shot = (y0 * 41) >> 12;          // exact /100 for y0<512
        int pos = y0 - shot * HWN;
        v = *(const float4*)&sb[((size_t)shot * CC + (kc + kk)) * HWN + pos];
      }
      bT[(y0 + 0) * 64 + (kk ^ (((y0 + 0) & 7) * 8))] = f2bf(v.x);
      bT[(y0 + 1) * 64 + (kk ^ (((y0 + 1) & 7) * 8))] = f2bf(v.y);
      bT[(y0 + 2) * 64 + (kk ^ (((y0 + 2) & 7) * 8))] = f2bf(v.z);
      bT[(y0 + 3) * 64 + (kk ^ (((y0 + 3) & 7) * 8))] = f2bf(v.w);
    }
    __syncthreads();
    // compute: 2 k-steps of 32, 7 x-tiles x 4 y-tiles per wave
    #pragma unroll
    for (int ks = 0; ks < 2; ++ks) {
      int colb = (ks * 32 + g * 8) ^ ((m & 7) * 8);
      bf16x8 af[7];
      #pragma unroll
      for (int ti = 0; ti < 7; ++ti)
        af[ti] = *(const bf16x8*)&aT[(ti * 16 + m) * 64 + colb];
      #pragma unroll
      for (int tj = 0; tj < 4; ++tj) {
        bf16x8 bfr = *(const bf16x8*)&bT[(wv * 64 + tj * 16 + m) * 64 + colb];
        #pragma unroll
        for (int ti = 0; ti < 7; ++ti)
          acc[ti][tj] = __builtin_amdgcn_mfma_f32_16x16x32_bf16(af[ti], bfr, acc[ti][tj], 0, 0, 0);
      }
    }
  }

  // ---- fused top-3 over y per row x, then sum over rows ----
  // D layout (verified): col(y) = lane&15, row(x) = 4*(lane>>4)+reg
  float sv[4];
  #pragma unroll
  for (int tj = 0; tj < 4; ++tj) {
    int y = wv * 64 + tj * 16 + m;
    sv[tj] = (y < YN) ? sinvb[y] : 0.f;
  }
  const float NEG = -1e30f;
  #pragma unroll
  for (int ti = 0; ti < 7; ++ti) {
    #pragma unroll
    for (int r = 0; r < 4; ++r) {
      float t1 = NEG, t2 = NEG, t3 = NEG;
      #pragma unroll
      for (int tj = 0; tj < 4; ++tj) {
        int y = wv * 64 + tj * 16 + m;
        float v = (y < YN) ? acc[ti][tj][r] * sv[tj] : NEG;
        ins3(v, t1, t2, t3);
      }
      // merge across the 16 lanes of this group (same row set)
      #pragma unroll
      for (int msk = 1; msk < 16; msk <<= 1) {
        float o1 = __shfl_xor(t1, msk);
        float o2 = __shfl_xor(t2, msk);
        float o3 = __shfl_xor(t3, msk);
        ins3(o1, t1, t2, t3);
        ins3(o2, t1, t2, t3);
        ins3(o3, t1, t2, t3);
      }
      if (m == 0) {
        int x = ti * 16 + g * 4 + r;
        part3[wv][x][0] = t1; part3[wv][x][1] = t2; part3[wv][x][2] = t3;
      }
    }
  }
  __syncthreads();
  if (tid < XPADN) {
    float t1 = NEG, t2 = NEG, t3 = NEG;
    #pragma unroll
    for (int w = 0; w < 8; ++w) {
      ins3(part3[w][tid][0], t1, t2, t3);
      ins3(part3[w][tid][1], t1, t2, t3);
      ins3(part3[w][tid][2], t1, t2, t3);
    }
    rowsum[tid] = (tid < HWN) ? (t1 + t2 + t3) : 0.f;
  }
  __syncthreads();
  if (tid < 64) {
    float sres = rowsum[tid] + ((tid + 64 < XPADN) ? rowsum[tid + 64] : 0.f);
    #pragma unroll
    for (int off = 32; off; off >>= 1) sres += __shfl_down(sres, off);
    if (tid == 0) out[(t * WQN + wq) * WAYN + way] = sres;
  }
}

extern "C" void kernel_launch(void* const* d_in, const int* in_sizes, int n_in,
                              void* d_out, int out_size, void* d_ws, size_t ws_size,
                              hipStream_t stream) {
  const float* q = (const float*)d_in[0];
  const float* s = (const float*)d_in[1];
  // ws: qinv (192000 f32) | sinv (10000 f32)  => 808 KB
  float* qinv = (float*)d_ws;
  float* sinv = qinv + (TT * WQN * CC);
  float* out = (float*)d_out;

  dn4_qinv<<<TT * WQN * CC / 4, 256, 0, stream>>>(q, qinv);
  dn4_sinv<<<TT * 25, 512, 0, stream>>>(s, sinv);
  dn4_main<<<TT * WAYN * WQN, 512, 0, stream>>>(q, s, qinv, sinv, out);
}

// Round 7
// 763.019 us; speedup vs baseline: 1.6730x; 1.6730x over previous
//
#include <hip/hip_runtime.h>
#include <hip/hip_bf16.h>

// Problem constants (from setup_inputs)
#define TT 4
#define WAYN 5
#define SHOTN 5
#define WQN 75          // way*query = 5*15
#define CC 640
#define HWN 100
#define YN 500          // shot*hw
#define YPADN 512
#define XPADN 112       // 100 padded to 7*16
#define KT 64           // K chunk
#define NKC 10          // CC/KT

#define A_CHUNK_B (XPADN * KT * 2)   // 14336 bytes
#define B_CHUNK_B (YPADN * KT * 2)   // 65536 bytes

typedef __attribute__((ext_vector_type(8))) short bf16x8;
typedef __attribute__((ext_vector_type(4))) float f32x4;

__device__ __forceinline__ unsigned short f2bf(float f) {
  unsigned int u = __float_as_uint(f);
  u += 0x7fffu + ((u >> 16) & 1u);   // RNE
  return (unsigned short)(u >> 16);
}

// async global->LDS, 16B per lane (dest must be wave-uniform base + lane*16)
__device__ __forceinline__ void gload16(const void* g, void* l) {
  __builtin_amdgcn_global_load_lds(
      (const __attribute__((address_space(1))) unsigned int*)g,
      (__attribute__((address_space(3))) unsigned int*)l, 16, 0, 0);
}

// branchless insert of v into sorted triple t1>=t2>=t3
__device__ __forceinline__ void ins3(float v, float& t1, float& t2, float& t3) {
  float a1 = fmaxf(t1, v), d1 = fminf(t1, v);
  float a2 = fmaxf(t2, d1), d2 = fminf(t2, d1);
  float a3 = fmaxf(t3, d2);
  t1 = a1; t2 = a2; t3 = a3;
}

// ---------- prep kernels: build swizzled bf16 operand images in ws ----------

// A image: per (tq, kci): [112 rows][64 k] bf16, elem (xx,kk) at kk^((xx&7)*8),
// value = q[tq, kc+kk, xx] * qinv[tq, kc+kk]; rows 100..111 zero.
// qinv computed in-block (norm over the 100 x's of each c).
__global__ __launch_bounds__(256)
void dn4_prepA(const float* __restrict__ q, unsigned short* __restrict__ Aswz) {
  __shared__ float qls[KT * 105];
  __shared__ float qpart[4][KT];
  __shared__ float qinvls[KT];
  int b = blockIdx.x;            // tq*NKC + kci
  int kci = b % NKC, tq = b / NKC;
  int tid = threadIdx.x;
  const float* qb = q + (size_t)tq * (CC * HWN) + (size_t)kci * KT * HWN;
  #pragma unroll
  for (int i = 0; i < 25; ++i) {     // 6400 contiguous floats, coalesced
    int idx = tid + i * 256;
    int c = idx / 100, x = idx - c * 100;
    qls[c * 105 + x] = qb[idx];
  }
  __syncthreads();
  {                                   // per-c sumsq over 100 x, 4-way split
    int c = tid & 63, qtr = tid >> 6;
    float ss = 0.f;
    const float* r = &qls[c * 105 + qtr * 25];
    #pragma unroll
    for (int j = 0; j < 25; ++j) { float v = r[j]; ss += v * v; }
    qpart[qtr][c] = ss;
  }
  __syncthreads();
  if (tid < KT) {
    float tot = qpart[0][tid] + qpart[1][tid] + qpart[2][tid] + qpart[3][tid];
    qinvls[tid] = 1.f / fmaxf(sqrtf(tot), 1e-12f);
  }
  __syncthreads();
  unsigned short* ob = Aswz + (size_t)b * (XPADN * KT);
  #pragma unroll
  for (int i = 0; i < 4; ++i) {
    int slot = tid + i * 256;        // 896 slots of (xx, kgroup)
    if (slot < XPADN * 8) {
      int xx = slot >> 3, kg = slot & 7;
      bf16x8 v = (bf16x8){0, 0, 0, 0, 0, 0, 0, 0};
      if (xx < HWN) {
        #pragma unroll
        for (int j = 0; j < 8; ++j) {
          int kk = kg * 8 + j;
          v[j] = (short)f2bf(qls[kk * 105 + xx] * qinvls[kk]);
        }
      }
      *(bf16x8*)&ob[xx * KT + ((kg * 8) ^ ((xx & 7) * 8))] = v;
    }
  }
}

// B image: per (tw, kci): [512 rows][64 k] bf16, elem (y,kk) at kk^((y&7)*8),
// value = s[t, way*5+shot, kc+kk, pos], y = shot*100+pos; rows 500..511 zero.
__global__ __launch_bounds__(256)
void dn4_prepB(const float* __restrict__ s, unsigned short* __restrict__ Bswz) {
  __shared__ float sls[KT * 105];
  int b = blockIdx.x;            // tw*NKC + kci
  int kci = b % NKC, tw = b / NKC;
  int tid = threadIdx.x;
  unsigned short* ob = Bswz + (size_t)b * (YPADN * KT);
  for (int shot = 0; shot < SHOTN; ++shot) {
    const float* sb = s + ((size_t)(tw * SHOTN + shot) * CC + (size_t)kci * KT) * HWN;
    __syncthreads();
    #pragma unroll
    for (int i = 0; i < 25; ++i) {
      int idx = tid + i * 256;
      int c = idx / 100, x = idx - c * 100;
      sls[c * 105 + x] = sb[idx];
    }
    __syncthreads();
    #pragma unroll
    for (int i = 0; i < 4; ++i) {
      int slot = tid + i * 256;      // 800 slots of (pos, kgroup)
      if (slot < HWN * 8) {
        int pos = slot >> 3, kg = slot & 7;
        int y = shot * HWN + pos;
        bf16x8 v;
        #pragma unroll
        for (int j = 0; j < 8; ++j)
          v[j] = (short)f2bf(sls[(kg * 8 + j) * 105 + pos]);
        *(bf16x8*)&ob[y * KT + ((kg * 8) ^ ((y & 7) * 8))] = v;
      }
    }
  }
  if (tid < (YPADN - YN) * 8) {      // zero pad rows
    int yy = YN + (tid >> 3), kg = tid & 7;
    *(bf16x8*)&ob[yy * KT + ((kg * 8) ^ ((yy & 7) * 8))] = (bf16x8){0,0,0,0,0,0,0,0};
  }
}

// sinv[t,way,y] = 1/max(||s[t,way,:,y]||,eps) — block per (t,sidx)
__global__ void dn4_sinv(const float* __restrict__ s, float* __restrict__ sinv) {
  __shared__ float ps[4][128];
  int b = blockIdx.x;                       // t*25 + sidx
  int cg = threadIdx.x >> 7, pos = threadIdx.x & 127;
  float ss = 0.f;
  if (pos < HWN) {
    const float* p = s + ((size_t)b * CC + cg * 160) * HWN + pos;
    #pragma unroll 8
    for (int c = 0; c < 160; ++c) { float v = p[c * HWN]; ss += v * v; }
  }
  ps[cg][pos] = ss;
  __syncthreads();
  if (cg == 0 && pos < HWN) {
    float tot = ps[0][pos] + ps[1][pos] + ps[2][pos] + ps[3][pos];
    int t = b / 25, sidx = b % 25, way = sidx / 5, shot = sidx % 5;
    sinv[(t * WAYN + way) * YN + shot * HWN + pos] = 1.f / fmaxf(sqrtf(tot), 1e-12f);
  }
}

// qinv kernel (fallback path only)
__global__ void dn4_qinv(const float* __restrict__ q, float* __restrict__ qinv) {
  int row = blockIdx.x * 4 + (threadIdx.x >> 6);
  int lane = threadIdx.x & 63;
  const float* p = q + (size_t)row * HWN;
  float ss = 0.f;
  if (lane < 50) { float2 v = ((const float2*)p)[lane]; ss = v.x * v.x + v.y * v.y; }
  #pragma unroll
  for (int off = 32; off; off >>= 1) ss += __shfl_down(ss, off);
  if (lane == 0) qinv[row] = 1.f / fmaxf(sqrtf(ss), 1e-12f);
}

// ---------- main kernel: gload_lds staging + MFMA + fused top-3 ----------
__global__ __launch_bounds__(512, 4)
void dn4_main(const unsigned short* __restrict__ Aswz,
              const unsigned short* __restrict__ Bswz,
              const float* __restrict__ sinv, float* __restrict__ out) {
  __shared__ __align__(16) unsigned char smem[A_CHUNK_B + B_CHUNK_B];  // 79872B

  int bid = blockIdx.x;
  int wq = bid % WQN;
  int tw = bid / WQN;          // t*WAYN + way (75 consecutive blocks share B)
  int t = tw / WAYN;
  int way = tw % WAYN;
  int tq = t * WQN + wq;

  int tid = threadIdx.x;
  int lane = tid & 63;
  int wv = tid >> 6;
  int m = lane & 15, g = lane >> 4;

  const unsigned char* gA = (const unsigned char*)Aswz + (size_t)tq * (NKC * A_CHUNK_B);
  const unsigned char* gB = (const unsigned char*)Bswz + (size_t)tw * (NKC * B_CHUNK_B);
  const float* sinvb = sinv + tw * YN;
  const unsigned short* aT = (const unsigned short*)smem;
  const unsigned short* bT = (const unsigned short*)(smem + A_CHUNK_B);

  f32x4 acc[7][4];
  #pragma unroll
  for (int i = 0; i < 7; ++i)
    #pragma unroll
    for (int j = 0; j < 4; ++j) acc[i][j] = (f32x4){0.f, 0.f, 0.f, 0.f};

  for (int kci = 0; kci < NKC; ++kci) {
    __syncthreads();                       // prev compute done reading smem
    const unsigned char* ga = gA + kci * A_CHUNK_B;
    for (int i = wv; i < 14; i += 8) {     // A: 14 KiB
      int off = i * 1024 + lane * 16;
      gload16(ga + off, smem + off);
    }
    const unsigned char* gb = gB + kci * B_CHUNK_B;
    #pragma unroll
    for (int j = 0; j < 8; ++j) {          // B: 64 KiB
      int off = (wv + j * 8) * 1024 + lane * 16;
      gload16(gb + off, smem + A_CHUNK_B + off);
    }
    __syncthreads();                       // drains vmcnt before ds_read
    #pragma unroll
    for (int ks = 0; ks < 2; ++ks) {
      int colb = (ks * 32 + g * 8) ^ ((m & 7) * 8);
      bf16x8 af[7];
      #pragma unroll
      for (int ti = 0; ti < 7; ++ti)
        af[ti] = *(const bf16x8*)&aT[(ti * 16 + m) * 64 + colb];
      #pragma unroll
      for (int tj = 0; tj < 4; ++tj) {
        bf16x8 bfr = *(const bf16x8*)&bT[(wv * 64 + tj * 16 + m) * 64 + colb];
        #pragma unroll
        for (int ti = 0; ti < 7; ++ti)
          acc[ti][tj] = __builtin_amdgcn_mfma_f32_16x16x32_bf16(af[ti], bfr, acc[ti][tj], 0, 0, 0);
      }
    }
  }
  __syncthreads();                         // all waves done reading tiles

  // epilogue arrays aliased into smem (tiles dead now)
  float* p3 = (float*)smem;                // [8][112][3]
  float* rowsum = p3 + 8 * XPADN * 3;      // [112]

  float sv[4];
  #pragma unroll
  for (int tj = 0; tj < 4; ++tj) {
    int y = wv * 64 + tj * 16 + m;
    sv[tj] = (y < YN) ? sinvb[y] : 0.f;
  }
  const float NEG = -1e30f;
  #pragma unroll
  for (int ti = 0; ti < 7; ++ti) {
    #pragma unroll
    for (int r = 0; r < 4; ++r) {
      float t1 = NEG, t2 = NEG, t3 = NEG;
      #pragma unroll
      for (int tj = 0; tj < 4; ++tj) {
        int y = wv * 64 + tj * 16 + m;
        float v = (y < YN) ? acc[ti][tj][r] * sv[tj] : NEG;
        ins3(v, t1, t2, t3);
      }
      #pragma unroll
      for (int msk = 1; msk < 16; msk <<= 1) {
        float o1 = __shfl_xor(t1, msk);
        float o2 = __shfl_xor(t2, msk);
        float o3 = __shfl_xor(t3, msk);
        ins3(o1, t1, t2, t3);
        ins3(o2, t1, t2, t3);
        ins3(o3, t1, t2, t3);
      }
      if (m == 0) {
        int x = ti * 16 + g * 4 + r;
        p3[(wv * XPADN + x) * 3 + 0] = t1;
        p3[(wv * XPADN + x) * 3 + 1] = t2;
        p3[(wv * XPADN + x) * 3 + 2] = t3;
      }
    }
  }
  __syncthreads();
  if (tid < XPADN) {
    float t1 = NEG, t2 = NEG, t3 = NEG;
    #pragma unroll
    for (int w = 0; w < 8; ++w) {
      ins3(p3[(w * XPADN + tid) * 3 + 0], t1, t2, t3);
      ins3(p3[(w * XPADN + tid) * 3 + 1], t1, t2, t3);
      ins3(p3[(w * XPADN + tid) * 3 + 2], t1, t2, t3);
    }
    rowsum[tid] = (tid < HWN) ? (t1 + t2 + t3) : 0.f;
  }
  __syncthreads();
  if (tid < 64) {
    float sres = rowsum[tid] + ((tid + 64 < XPADN) ? rowsum[tid + 64] : 0.f);
    #pragma unroll
    for (int off = 32; off; off >>= 1) sres += __shfl_down(sres, off);
    if (tid == 0) out[tq * WAYN + way] = sres;
  }
}

// ---------- fallback: round-3 verified all-in-one kernel ----------
__global__ __launch_bounds__(512, 2)
void dn4_main_fb(const float* __restrict__ q, const float* __restrict__ s,
                 const float* __restrict__ qinv, const float* __restrict__ sinv,
                 float* __restrict__ out) {
  __shared__ __align__(16) unsigned short aT[XPADN * 64];
  __shared__ __align__(16) unsigned short bT[YPADN * 64];
  __shared__ float part3[8][XPADN][3];
  __shared__ float rowsum[XPADN];

  int bid = blockIdx.x;
  int wq = bid % WQN;
  int tw = bid / WQN;
  int way = tw % WAYN;
  int t = tw / WAYN;

  int tid = threadIdx.x;
  int lane = tid & 63;
  int wv = tid >> 6;
  int m = lane & 15, g = lane >> 4;

  const float* qb = q + ((size_t)(t * WQN + wq) * CC) * HWN;
  const float* sb = s + ((size_t)(t * 25 + way * SHOTN) * CC) * HWN;
  const float* qinvb = qinv + (t * WQN + wq) * CC;
  const float* sinvb = sinv + (t * WAYN + way) * YN;

  f32x4 acc[7][4];
  #pragma unroll
  for (int i = 0; i < 7; ++i)
    #pragma unroll
    for (int j = 0; j < 4; ++j) acc[i][j] = (f32x4){0.f, 0.f, 0.f, 0.f};

  for (int kc = 0; kc < CC; kc += KT) {
    __syncthreads();
    #pragma unroll
    for (int it = 0; it < 16; ++it) {
      int e = tid + it * 512;
      int kk = e >> 7, xx = e & 127;
      if (xx < XPADN) {
        float v = 0.f;
        if (xx < HWN) v = qb[(kc + kk) * HWN + xx] * qinvb[kc + kk];
        aT[xx * 64 + (kk ^ ((xx & 7) * 8))] = f2bf(v);
      }
    }
    #pragma unroll
    for (int it = 0; it < 16; ++it) {
      int e = tid + it * 512;
      int kk = e >> 7, yg = e & 127;
      int y0 = yg * 4;
      float4 v = make_float4(0.f, 0.f, 0.f, 0.f);
      if (y0 < YN) {
        int shot = (y0 * 41) >> 12;
        int pos = y0 - shot * HWN;
        v = *(const float4*)&sb[((size_t)shot * CC + (kc + kk)) * HWN + pos];
      }
      bT[(y0 + 0) * 64 + (kk ^ (((y0 + 0) & 7) * 8))] = f2bf(v.x);
      bT[(y0 + 1) * 64 + (kk ^ (((y0 + 1) & 7) * 8))] = f2bf(v.y);
      bT[(y0 + 2) * 64 + (kk ^ (((y0 + 2) & 7) * 8))] = f2bf(v.z);
      bT[(y0 + 3) * 64 + (kk ^ (((y0 + 3) & 7) * 8))] = f2bf(v.w);
    }
    __syncthreads();
    #pragma unroll
    for (int ks = 0; ks < 2; ++ks) {
      int colb = (ks * 32 + g * 8) ^ ((m & 7) * 8);
      bf16x8 af[7];
      #pragma unroll
      for (int ti = 0; ti < 7; ++ti)
        af[ti] = *(const bf16x8*)&aT[(ti * 16 + m) * 64 + colb];
      #pragma unroll
      for (int tj = 0; tj < 4; ++tj) {
        bf16x8 bfr = *(const bf16x8*)&bT[(wv * 64 + tj * 16 + m) * 64 + colb];
        #pragma unroll
        for (int ti = 0; ti < 7; ++ti)
          acc[ti][tj] = __builtin_amdgcn_mfma_f32_16x16x32_bf16(af[ti], bfr, acc[ti][tj], 0, 0, 0);
      }
    }
  }

  float sv[4];
  #pragma unroll
  for (int tj = 0; tj < 4; ++tj) {
    int y = wv * 64 + tj * 16 + m;
    sv[tj] = (y < YN) ? sinvb[y] : 0.f;
  }
  const float NEG = -1e30f;
  #pragma unroll
  for (int ti = 0; ti < 7; ++ti) {
    #pragma unroll
    for (int r = 0; r < 4; ++r) {
      float t1 = NEG, t2 = NEG, t3 = NEG;
      #pragma unroll
      for (int tj = 0; tj < 4; ++tj) {
        int y = wv * 64 + tj * 16 + m;
        float v = (y < YN) ? acc[ti][tj][r] * sv[tj] : NEG;
        ins3(v, t1, t2, t3);
      }
      #pragma unroll
      for (int msk = 1; msk < 16; msk <<= 1) {
        float o1 = __shfl_xor(t1, msk);
        float o2 = __shfl_xor(t2, msk);
        float o3 = __shfl_xor(t3, msk);
        ins3(o1, t1, t2, t3);
        ins3(o2, t1, t2, t3);
        ins3(o3, t1, t2, t3);
      }
      if (m == 0) {
        int x = ti * 16 + g * 4 + r;
        part3[wv][x][0] = t1; part3[wv][x][1] = t2; part3[wv][x][2] = t3;
      }
    }
  }
  __syncthreads();
  if (tid < XPADN) {
    float t1 = NEG, t2 = NEG, t3 = NEG;
    #pragma unroll
    for (int w = 0; w < 8; ++w) {
      ins3(part3[w][tid][0], t1, t2, t3);
      ins3(part3[w][tid][1], t1, t2, t3);
      ins3(part3[w][tid][2], t1, t2, t3);
    }
    rowsum[tid] = (tid < HWN) ? (t1 + t2 + t3) : 0.f;
  }
  __syncthreads();
  if (tid < 64) {
    float sres = rowsum[tid] + ((tid + 64 < XPADN) ? rowsum[tid + 64] : 0.f);
    #pragma unroll
    for (int off = 32; off; off >>= 1) sres += __shfl_down(sres, off);
    if (tid == 0) out[(t * WQN + wq) * WAYN + way] = sres;
  }
}

extern "C" void kernel_launch(void* const* d_in, const int* in_sizes, int n_in,
                              void* d_out, int out_size, void* d_ws, size_t ws_size,
                              hipStream_t stream) {
  const float* q = (const float*)d_in[0];
  const float* s = (const float*)d_in[1];
  // ws layout: qinv f32[192000] @0 | sinv f32[10000] @768000B |
  //            Aswz bf16 @808000B (43,008,000B) | Bswz bf16 @43,816,000B (13,107,200B)
  float* qinv = (float*)d_ws;
  float* sinv = (float*)((char*)d_ws + 768000);
  unsigned short* Aswz = (unsigned short*)((char*)d_ws + 808000);
  unsigned short* Bswz = (unsigned short*)((char*)d_ws + 43816000);
  float* out = (float*)d_out;
  const size_t REQUIRED = 56923200ull;

  dn4_sinv<<<TT * 25, 512, 0, stream>>>(s, sinv);
  if (ws_size >= REQUIRED) {
    dn4_prepA<<<TT * WQN * NKC, 256, 0, stream>>>(q, Aswz);
    dn4_prepB<<<TT * WAYN * NKC, 256, 0, stream>>>(s, Bswz);
    dn4_main<<<TT * WAYN * WQN, 512, 0, stream>>>(Aswz, Bswz, sinv, out);
  } else {
    dn4_qinv<<<TT * WQN * CC / 4, 256, 0, stream>>>(q, qinv);
    dn4_main_fb<<<TT * WAYN * WQN, 512, 0, stream>>>(q, s, qinv, sinv, out);
  }
}

// Round 10
// 324.777 us; speedup vs baseline: 3.9304x; 2.3494x over previous
//
#include <hip/hip_runtime.h>
#include <hip/hip_bf16.h>

// Problem constants (from setup_inputs)
#define TT 4
#define WAYN 5
#define SHOTN 5
#define WQN 75          // way*query = 5*15
#define CC 640
#define HWN 100
#define YN 500          // shot*hw
#define YPADN 512
#define XPADN 112       // 100 padded to 7*16
#define KT 64           // K chunk
#define NKC 10          // CC/KT

#define A_CHUNK_B (XPADN * KT * 2)   // 14336 bytes
#define B_CHUNK_B (YPADN * KT * 2)   // 65536 bytes
#define CHUNK_B (A_CHUNK_B + B_CHUNK_B)

typedef __attribute__((ext_vector_type(8))) short bf16x8;
typedef __attribute__((ext_vector_type(4))) float f32x4;

__device__ __forceinline__ unsigned short f2bf(float f) {
  unsigned int u = __float_as_uint(f);
  u += 0x7fffu + ((u >> 16) & 1u);   // RNE
  return (unsigned short)(u >> 16);
}

// async global->LDS, 16B per lane (dest must be wave-uniform base + lane*16)
__device__ __forceinline__ void gload16(const void* g, void* l) {
  __builtin_amdgcn_global_load_lds(
      (const __attribute__((address_space(1))) unsigned int*)g,
      (__attribute__((address_space(3))) unsigned int*)l, 16, 0, 0);
}

// branchless insert of v into sorted triple t1>=t2>=t3
__device__ __forceinline__ void ins3(float v, float& t1, float& t2, float& t3) {
  float a1 = fmaxf(t1, v), d1 = fminf(t1, v);
  float a2 = fmaxf(t2, d1), d2 = fminf(t2, d1);
  float a3 = fmaxf(t3, d2);
  t1 = a1; t2 = a2; t3 = a3;
}

// ---------- prep kernels: build swizzled bf16 operand images in ws ----------

// A image: per (tq, kci): [112 rows][64 k] bf16, elem (xx,kk) at kk^((xx&7)*8),
// value = q[tq, kc+kk, xx] * qinv[tq, kc+kk]; rows 100..111 zero.
__global__ __launch_bounds__(256)
void dn4_prepA(const float* __restrict__ q, unsigned short* __restrict__ Aswz) {
  __shared__ float qls[KT * 105];
  __shared__ float qpart[4][KT];
  __shared__ float qinvls[KT];
  int b = blockIdx.x;            // tq*NKC + kci
  int kci = b % NKC, tq = b / NKC;
  int tid = threadIdx.x;
  const float* qb = q + (size_t)tq * (CC * HWN) + (size_t)kci * KT * HWN;
  #pragma unroll
  for (int i = 0; i < 25; ++i) {     // 6400 contiguous floats, coalesced
    int idx = tid + i * 256;
    int c = idx / 100, x = idx - c * 100;
    qls[c * 105 + x] = qb[idx];
  }
  __syncthreads();
  {                                   // per-c sumsq over 100 x, 4-way split
    int c = tid & 63, qtr = tid >> 6;
    float ss = 0.f;
    const float* r = &qls[c * 105 + qtr * 25];
    #pragma unroll
    for (int j = 0; j < 25; ++j) { float v = r[j]; ss += v * v; }
    qpart[qtr][c] = ss;
  }
  __syncthreads();
  if (tid < KT) {
    float tot = qpart[0][tid] + qpart[1][tid] + qpart[2][tid] + qpart[3][tid];
    qinvls[tid] = 1.f / fmaxf(sqrtf(tot), 1e-12f);
  }
  __syncthreads();
  unsigned short* ob = Aswz + (size_t)b * (XPADN * KT);
  #pragma unroll
  for (int i = 0; i < 4; ++i) {
    int slot = tid + i * 256;        // 896 slots of (xx, kgroup)
    if (slot < XPADN * 8) {
      int xx = slot >> 3, kg = slot & 7;
      bf16x8 v = (bf16x8){0, 0, 0, 0, 0, 0, 0, 0};
      if (xx < HWN) {
        #pragma unroll
        for (int j = 0; j < 8; ++j) {
          int kk = kg * 8 + j;
          v[j] = (short)f2bf(qls[kk * 105 + xx] * qinvls[kk]);
        }
      }
      *(bf16x8*)&ob[xx * KT + ((kg * 8) ^ ((xx & 7) * 8))] = v;
    }
  }
}

// B image: per (tw, kci): [512 rows][64 k] bf16, elem (y,kk) at kk^((y&7)*8),
// value = s[t, way*5+shot, kc+kk, pos], y = shot*100+pos; rows 500..511 zero.
// ALSO emits ssqpart[tw][kci][y] = sum over this chunk's 64 c's of s^2 (for sinv).
__global__ __launch_bounds__(256)
void dn4_prepB(const float* __restrict__ s, unsigned short* __restrict__ Bswz,
               float* __restrict__ ssqpart) {
  __shared__ float sls[KT * 105];
  int b = blockIdx.x;            // tw*NKC + kci
  int kci = b % NKC, tw = b / NKC;
  int tid = threadIdx.x;
  unsigned short* ob = Bswz + (size_t)b * (YPADN * KT);
  float* sqb = ssqpart + (size_t)b * YPADN;
  for (int shot = 0; shot < SHOTN; ++shot) {
    const float* sb = s + ((size_t)(tw * SHOTN + shot) * CC + (size_t)kci * KT) * HWN;
    __syncthreads();
    #pragma unroll
    for (int i = 0; i < 25; ++i) {
      int idx = tid + i * 256;
      int c = idx / 100, x = idx - c * 100;
      sls[c * 105 + x] = sb[idx];
    }
    __syncthreads();
    #pragma unroll
    for (int i = 0; i < 4; ++i) {
      int slot = tid + i * 256;      // 800 slots of (pos, kgroup)
      if (slot < HWN * 8) {
        int pos = slot >> 3, kg = slot & 7;
        int y = shot * HWN + pos;
        bf16x8 v;
        #pragma unroll
        for (int j = 0; j < 8; ++j)
          v[j] = (short)f2bf(sls[(kg * 8 + j) * 105 + pos]);
        *(bf16x8*)&ob[y * KT + ((kg * 8) ^ ((y & 7) * 8))] = v;
      }
    }
    if (tid < HWN) {                 // sumsq over this chunk's 64 c's
      float ss = 0.f;
      #pragma unroll
      for (int c = 0; c < KT; ++c) { float v = sls[c * 105 + tid]; ss += v * v; }
      sqb[shot * HWN + tid] = ss;
    }
  }
  if (tid < (YPADN - YN) * 8) {      // zero pad rows
    int yy = YN + (tid >> 3), kg = tid & 7;
    *(bf16x8*)&ob[yy * KT + ((kg * 8) ^ ((yy & 7) * 8))] = (bf16x8){0,0,0,0,0,0,0,0};
  }
}

// reduce ssqpart over kci -> sinv[tw][y]
__global__ void dn4_sinv2(const float* __restrict__ ssqpart, float* __restrict__ sinv) {
  int tw = blockIdx.x, y = threadIdx.x;
  if (y < YN) {
    float tot = 0.f;
    #pragma unroll
    for (int k = 0; k < NKC; ++k) tot += ssqpart[((size_t)tw * NKC + k) * YPADN + y];
    sinv[tw * YN + y] = 1.f / fmaxf(sqrtf(tot), 1e-12f);
  }
}

// ---- fallback-path helpers (round-3 verified) ----
__global__ void dn4_sinv(const float* __restrict__ s, float* __restrict__ sinv) {
  __shared__ float ps[4][128];
  int b = blockIdx.x;
  int cg = threadIdx.x >> 7, pos = threadIdx.x & 127;
  float ss = 0.f;
  if (pos < HWN) {
    const float* p = s + ((size_t)b * CC + cg * 160) * HWN + pos;
    #pragma unroll 8
    for (int c = 0; c < 160; ++c) { float v = p[c * HWN]; ss += v * v; }
  }
  ps[cg][pos] = ss;
  __syncthreads();
  if (cg == 0 && pos < HWN) {
    float tot = ps[0][pos] + ps[1][pos] + ps[2][pos] + ps[3][pos];
    int t = b / 25, sidx = b % 25, way = sidx / 5, shot = sidx % 5;
    sinv[(t * WAYN + way) * YN + shot * HWN + pos] = 1.f / fmaxf(sqrtf(tot), 1e-12f);
  }
}

__global__ void dn4_qinv(const float* __restrict__ q, float* __restrict__ qinv) {
  int row = blockIdx.x * 4 + (threadIdx.x >> 6);
  int lane = threadIdx.x & 63;
  const float* p = q + (size_t)row * HWN;
  float ss = 0.f;
  if (lane < 50) { float2 v = ((const float2*)p)[lane]; ss = v.x * v.x + v.y * v.y; }
  #pragma unroll
  for (int off = 32; off; off >>= 1) ss += __shfl_down(ss, off);
  if (lane == 0) qinv[row] = 1.f / fmaxf(sqrtf(ss), 1e-12f);
}

// ---------- main kernel: double-buffered gload_lds + MFMA + fused top-3 ----------
__global__ __launch_bounds__(512, 2)
void dn4_main(const unsigned short* __restrict__ Aswz,
              const unsigned short* __restrict__ Bswz,
              const float* __restrict__ sinv, float* __restrict__ out) {
  __shared__ __align__(16) unsigned char smem[2][CHUNK_B];  // 159744 B

  int bid = blockIdx.x;
  int wq = bid % WQN;
  int tw = bid / WQN;          // t*WAYN + way (75 consecutive blocks share B)
  int t = tw / WAYN;
  int way = tw % WAYN;
  int tq = t * WQN + wq;

  int tid = threadIdx.x;
  int lane = tid & 63;
  int wv = tid >> 6;
  int m = lane & 15, g = lane >> 4;

  const unsigned char* gA = (const unsigned char*)Aswz + (size_t)tq * (NKC * A_CHUNK_B);
  const unsigned char* gB = (const unsigned char*)Bswz + (size_t)tw * (NKC * B_CHUNK_B);
  const float* sinvb = sinv + tw * YN;

  f32x4 acc[7][4];
  #pragma unroll
  for (int i = 0; i < 7; ++i)
    #pragma unroll
    for (int j = 0; j < 4; ++j) acc[i][j] = (f32x4){0.f, 0.f, 0.f, 0.f};

  // per-wave staging: waves 0-6 issue 2 A-loads + 8 B-loads (10); wave 7: 8.
#define STAGE(kci_, buf_)                                                     \
  {                                                                           \
    const unsigned char* ga = gA + (kci_) * A_CHUNK_B;                        \
    unsigned char* lb = smem[buf_];                                           \
    if (wv < 7) {                                                             \
      int oa = wv * 2048 + lane * 16;                                         \
      gload16(ga + oa, lb + oa);                                              \
      gload16(ga + oa + 1024, lb + oa + 1024);                                \
    }                                                                         \
    const unsigned char* gb = gB + (kci_) * B_CHUNK_B;                        \
    _Pragma("unroll")                                                         \
    for (int j = 0; j < 8; ++j) {                                             \
      int ob = (wv + j * 8) * 1024 + lane * 16;                               \
      gload16(gb + ob, lb + A_CHUNK_B + ob);                                  \
    }                                                                         \
  }

  STAGE(0, 0);
  for (int kci = 0; kci < NKC; ++kci) {
    int cur = kci & 1;
    if (kci + 1 < NKC) {
      STAGE(kci + 1, cur ^ 1);
      // wait for CURRENT chunk's loads (oldest); leave next chunk's in flight
      if (wv < 7) asm volatile("s_waitcnt vmcnt(10)" ::: "memory");
      else        asm volatile("s_waitcnt vmcnt(8)" ::: "memory");
    } else {
      asm volatile("s_waitcnt vmcnt(0)" ::: "memory");
    }
    __builtin_amdgcn_s_barrier();          // all waves' current-chunk data landed
    __builtin_amdgcn_sched_barrier(0);     // no ds_read hoists above (rule #18)
    const unsigned short* aT = (const unsigned short*)smem[cur];
    const unsigned short* bT = (const unsigned short*)(smem[cur] + A_CHUNK_B);
    #pragma unroll
    for (int ks = 0; ks < 2; ++ks) {
      int colb = (ks * 32 + g * 8) ^ ((m & 7) * 8);
      bf16x8 af[7];
      #pragma unroll
      for (int ti = 0; ti < 7; ++ti)
        af[ti] = *(const bf16x8*)&aT[(ti * 16 + m) * 64 + colb];
      #pragma unroll
      for (int tj = 0; tj < 4; ++tj) {
        bf16x8 bfr = *(const bf16x8*)&bT[(wv * 64 + tj * 16 + m) * 64 + colb];
        #pragma unroll
        for (int ti = 0; ti < 7; ++ti)
          acc[ti][tj] = __builtin_amdgcn_mfma_f32_16x16x32_bf16(af[ti], bfr, acc[ti][tj], 0, 0, 0);
      }
    }
    __builtin_amdgcn_sched_barrier(0);     // compute stays above end-barrier
    __builtin_amdgcn_s_barrier();          // done reading smem[cur]; next iter overwrites it
    __builtin_amdgcn_sched_barrier(0);     // next STAGE stays below
  }

  // epilogue arrays aliased into smem (tiles dead; last barrier passed, vmcnt 0)
  float* p3 = (float*)smem;                // [8][112][3]
  float* rowsum = p3 + 8 * XPADN * 3;      // [112]

  float sv[4];
  #pragma unroll
  for (int tj = 0; tj < 4; ++tj) {
    int y = wv * 64 + tj * 16 + m;
    sv[tj] = (y < YN) ? sinvb[y] : 0.f;
  }
  const float NEG = -1e30f;
  #pragma unroll
  for (int ti = 0; ti < 7; ++ti) {
    #pragma unroll
    for (int r = 0; r < 4; ++r) {
      float t1 = NEG, t2 = NEG, t3 = NEG;
      #pragma unroll
      for (int tj = 0; tj < 4; ++tj) {
        int y = wv * 64 + tj * 16 + m;
        float v = (y < YN) ? acc[ti][tj][r] * sv[tj] : NEG;
        ins3(v, t1, t2, t3);
      }
      #pragma unroll
      for (int msk = 1; msk < 16; msk <<= 1) {
        float o1 = __shfl_xor(t1, msk);
        float o2 = __shfl_xor(t2, msk);
        float o3 = __shfl_xor(t3, msk);
        ins3(o1, t1, t2, t3);
        ins3(o2, t1, t2, t3);
        ins3(o3, t1, t2, t3);
      }
      if (m == 0) {
        int x = ti * 16 + g * 4 + r;
        p3[(wv * XPADN + x) * 3 + 0] = t1;
        p3[(wv * XPADN + x) * 3 + 1] = t2;
        p3[(wv * XPADN + x) * 3 + 2] = t3;
      }
    }
  }
  __syncthreads();
  if (tid < XPADN) {
    float t1 = NEG, t2 = NEG, t3 = NEG;
    #pragma unroll
    for (int w = 0; w < 8; ++w) {
      ins3(p3[(w * XPADN + tid) * 3 + 0], t1, t2, t3);
      ins3(p3[(w * XPADN + tid) * 3 + 1], t1, t2, t3);
      ins3(p3[(w * XPADN + tid) * 3 + 2], t1, t2, t3);
    }
    rowsum[tid] = (tid < HWN) ? (t1 + t2 + t3) : 0.f;
  }
  __syncthreads();
  if (tid < 64) {
    float sres = rowsum[tid] + ((tid + 64 < XPADN) ? rowsum[tid + 64] : 0.f);
    #pragma unroll
    for (int off = 32; off; off >>= 1) sres += __shfl_down(sres, off);
    if (tid == 0) out[tq * WAYN + way] = sres;
  }
}

// ---------- fallback: round-3 verified all-in-one kernel ----------
__global__ __launch_bounds__(512, 2)
void dn4_main_fb(const float* __restrict__ q, const float* __restrict__ s,
                 const float* __restrict__ qinv, const float* __restrict__ sinv,
                 float* __restrict__ out) {
  __shared__ __align__(16) unsigned short aT[XPADN * 64];
  __shared__ __align__(16) unsigned short bT[YPADN * 64];
  __shared__ float part3[8][XPADN][3];
  __shared__ float rowsum[XPADN];

  int bid = blockIdx.x;
  int wq = bid % WQN;
  int tw = bid / WQN;
  int way = tw % WAYN;
  int t = tw / WAYN;

  int tid = threadIdx.x;
  int lane = tid & 63;
  int wv = tid >> 6;
  int m = lane & 15, g = lane >> 4;

  const float* qb = q + ((size_t)(t * WQN + wq) * CC) * HWN;
  const float* sb = s + ((size_t)(t * 25 + way * SHOTN) * CC) * HWN;
  const float* qinvb = qinv + (t * WQN + wq) * CC;
  const float* sinvb = sinv + (t * WAYN + way) * YN;

  f32x4 acc[7][4];
  #pragma unroll
  for (int i = 0; i < 7; ++i)
    #pragma unroll
    for (int j = 0; j < 4; ++j) acc[i][j] = (f32x4){0.f, 0.f, 0.f, 0.f};

  for (int kc = 0; kc < CC; kc += KT) {
    __syncthreads();
    #pragma unroll
    for (int it = 0; it < 16; ++it) {
      int e = tid + it * 512;
      int kk = e >> 7, xx = e & 127;
      if (xx < XPADN) {
        float v = 0.f;
        if (xx < HWN) v = qb[(kc + kk) * HWN + xx] * qinvb[kc + kk];
        aT[xx * 64 + (kk ^ ((xx & 7) * 8))] = f2bf(v);
      }
    }
    #pragma unroll
    for (int it = 0; it < 16; ++it) {
      int e = tid + it * 512;
      int kk = e >> 7, yg = e & 127;
      int y0 = yg * 4;
      float4 v = make_float4(0.f, 0.f, 0.f, 0.f);
      if (y0 < YN) {
        int shot = (y0 * 41) >> 12;
        int pos = y0 - shot * HWN;
        v = *(const float4*)&sb[((size_t)shot * CC + (kc + kk)) * HWN + pos];
      }
      bT[(y0 + 0) * 64 + (kk ^ (((y0 + 0) & 7) * 8))] = f2bf(v.x);
      bT[(y0 + 1) * 64 + (kk ^ (((y0 + 1) & 7) * 8))] = f2bf(v.y);
      bT[(y0 + 2) * 64 + (kk ^ (((y0 + 2) & 7) * 8))] = f2bf(v.z);
      bT[(y0 + 3) * 64 + (kk ^ (((y0 + 3) & 7) * 8))] = f2bf(v.w);
    }
    __syncthreads();
    #pragma unroll
    for (int ks = 0; ks < 2; ++ks) {
      int colb = (ks * 32 + g * 8) ^ ((m & 7) * 8);
      bf16x8 af[7];
      #pragma unroll
      for (int ti = 0; ti < 7; ++ti)
        af[ti] = *(const bf16x8*)&aT[(ti * 16 + m) * 64 + colb];
      #pragma unroll
      for (int tj = 0; tj < 4; ++tj) {
        bf16x8 bfr = *(const bf16x8*)&bT[(wv * 64 + tj * 16 + m) * 64 + colb];
        #pragma unroll
        for (int ti = 0; ti < 7; ++ti)
          acc[ti][tj] = __builtin_amdgcn_mfma_f32_16x16x32_bf16(af[ti], bfr, acc[ti][tj], 0, 0, 0);
      }
    }
  }

  float sv[4];
  #pragma unroll
  for (int tj = 0; tj < 4; ++tj) {
    int y = wv * 64 + tj * 16 + m;
    sv[tj] = (y < YN) ? sinvb[y] : 0.f;
  }
  const float NEG = -1e30f;
  #pragma unroll
  for (int ti = 0; ti < 7; ++ti) {
    #pragma unroll
    for (int r = 0; r < 4; ++r) {
      float t1 = NEG, t2 = NEG, t3 = NEG;
      #pragma unroll
      for (int tj = 0; tj < 4; ++tj) {
        int y = wv * 64 + tj * 16 + m;
        float v = (y < YN) ? acc[ti][tj][r] * sv[tj] : NEG;
        ins3(v, t1, t2, t3);
      }
      #pragma unroll
      for (int msk = 1; msk < 16; msk <<= 1) {
        float o1 = __shfl_xor(t1, msk);
        float o2 = __shfl_xor(t2, msk);
        float o3 = __shfl_xor(t3, msk);
        ins3(o1, t1, t2, t3);
        ins3(o2, t1, t2, t3);
        ins3(o3, t1, t2, t3);
      }
      if (m == 0) {
        int x = ti * 16 + g * 4 + r;
        part3[wv][x][0] = t1; part3[wv][x][1] = t2; part3[wv][x][2] = t3;
      }
    }
  }
  __syncthreads();
  if (tid < XPADN) {
    float t1 = NEG, t2 = NEG, t3 = NEG;
    #pragma unroll
    for (int w = 0; w < 8; ++w) {
      ins3(part3[w][tid][0], t1, t2, t3);
      ins3(part3[w][tid][1], t1, t2, t3);
      ins3(part3[w][tid][2], t1, t2, t3);
    }
    rowsum[tid] = (tid < HWN) ? (t1 + t2 + t3) : 0.f;
  }
  __syncthreads();
  if (tid < 64) {
    float sres = rowsum[tid] + ((tid + 64 < XPADN) ? rowsum[tid + 64] : 0.f);
    #pragma unroll
    for (int off = 32; off; off >>= 1) sres += __shfl_down(sres, off);
    if (tid == 0) out[(t * WQN + wq) * WAYN + way] = sres;
  }
}

extern "C" void kernel_launch(void* const* d_in, const int* in_sizes, int n_in,
                              void* d_out, int out_size, void* d_ws, size_t ws_size,
                              hipStream_t stream) {
  const float* q = (const float*)d_in[0];
  const float* s = (const float*)d_in[1];
  float* out = (float*)d_out;

  // main-path ws layout:
  //   sinv    f32[10000]        @ 0        (40000 B)
  //   ssqpart f32[200*512]      @ 40960    (409600 B)
  //   Aswz    bf16[300*10*7168] @ 450560   (43,008,000 B)
  //   Bswz    bf16[20*10*32768] @ 43458560 (13,107,200 B)  => REQUIRED 56,565,760
  const size_t REQUIRED = 56565760ull;

  if (ws_size >= REQUIRED) {
    float* sinv = (float*)d_ws;
    float* ssqpart = (float*)((char*)d_ws + 40960);
    unsigned short* Aswz = (unsigned short*)((char*)d_ws + 450560);
    unsigned short* Bswz = (unsigned short*)((char*)d_ws + 43458560);
    dn4_prepA<<<TT * WQN * NKC, 256, 0, stream>>>(q, Aswz);
    dn4_prepB<<<TT * WAYN * NKC, 256, 0, stream>>>(s, Bswz, ssqpart);
    dn4_sinv2<<<TT * WAYN, 512, 0, stream>>>(ssqpart, sinv);
    dn4_main<<<TT * WAYN * WQN, 512, 0, stream>>>(Aswz, Bswz, sinv, out);
  } else {
    float* qinv = (float*)d_ws;
    float* sinv = (float*)((char*)d_ws + 768000);
    dn4_qinv<<<TT * WQN * CC / 4, 256, 0, stream>>>(q, qinv);
    dn4_sinv<<<TT * 25, 512, 0, stream>>>(s, sinv);
    dn4_main_fb<<<TT * WAYN * WQN, 512, 0, stream>>>(q, s, qinv, sinv, out);
  }
}